// Round 14
// baseline (762.845 us; speedup 1.0000x reference)
//
#include <hip/hip_runtime.h>

constexpr int NN = 50000;
constexpr int EE = 800000;
constexpr int DH = 128;
constexpr int DE = 16;
constexpr int DM = 128;

typedef short bf16x8 __attribute__((ext_vector_type(8)));
typedef float f32x4 __attribute__((ext_vector_type(4)));

__device__ __forceinline__ float silu_f(float z) {
  return __fdividef(z, 1.0f + __expf(-z));
}
__device__ __forceinline__ unsigned short bf16rne(float f) {
  unsigned u = __float_as_uint(f);
  return (unsigned short)((u + 0x7FFFu + ((u >> 16) & 1u)) >> 16);
}

// --- prep: transpose weights to bf16 [n][k] row-major in global ---
__global__ __launch_bounds__(256)
void prep_wt_kernel(const float* __restrict__ We1, const float* __restrict__ Wh1,
                    const float* __restrict__ Wh2,
                    unsigned short* __restrict__ WeaT, unsigned short* __restrict__ WebT,
                    unsigned short* __restrict__ Wh1T, unsigned short* __restrict__ Wh2T)
{
  int i = blockIdx.x * 256 + threadIdx.x;
  if (i < 16384) {
    int n = i >> 7, k = i & 127;
    WeaT[n * 128 + k] = bf16rne(We1[k * DM + n]);
    WebT[n * 128 + k] = bf16rne(We1[(DH + k) * DM + n]);
    Wh2T[n * 128 + k] = bf16rne(Wh2[k * DM + n]);
  }
  if (i < 32768) {
    int n = i >> 8, k = i & 255;
    Wh1T[n * 256 + k] = bf16rne(Wh1[k * DM + n]);
  }
}

// --- node precompute via MFMA: u = h @ We1[0:128], w = h @ We1[128:256] ---
__global__ __launch_bounds__(256, 2)
void node_pre_mfma(const float* __restrict__ h,
                   const unsigned short* __restrict__ WeaT,
                   const unsigned short* __restrict__ WebT,
                   float* __restrict__ u, float* __restrict__ w)
{
  __shared__ unsigned short Ba[DM * DM];  // swizzled: byte ^= (n&7)<<4
  __shared__ unsigned short Bb[DM * DM];
  const int tid = threadIdx.x;
  for (int c = tid; c < 2048; c += 256) {
    int n = c >> 4, ck = c & 15;
    int sb = (n * 256 + ck * 16) ^ ((n & 7) << 4);
    *(bf16x8*)((char*)Ba + sb) = ((const bf16x8*)WeaT)[c];
    *(bf16x8*)((char*)Bb + sb) = ((const bf16x8*)WebT)[c];
  }
  __syncthreads();
  const int lane = tid & 63, wv = tid >> 6;
  const int cl = lane & 15, kg = lane >> 4;
  const int waveId = blockIdx.x * 4 + wv, nW = gridDim.x * 4;
  for (int tile = waveId; tile < NN / 16; tile += nW) {
    const long rbase = (long)tile * 16;
    bf16x8 af[4];
#pragma unroll
    for (int kk = 0; kk < 4; ++kk) {
      const float* hp = &h[(rbase + cl) * DH + kk * 32 + kg * 8];
      float4 a0 = *(const float4*)hp;
      float4 a1 = *(const float4*)(hp + 4);
      bf16x8 v;
      v[0] = (short)bf16rne(a0.x); v[1] = (short)bf16rne(a0.y);
      v[2] = (short)bf16rne(a0.z); v[3] = (short)bf16rne(a0.w);
      v[4] = (short)bf16rne(a1.x); v[5] = (short)bf16rne(a1.y);
      v[6] = (short)bf16rne(a1.z); v[7] = (short)bf16rne(a1.w);
      af[kk] = v;
    }
#pragma unroll
    for (int b = 0; b < 8; ++b) {
      f32x4 acc = (f32x4){0.f, 0.f, 0.f, 0.f};
      f32x4 acw = (f32x4){0.f, 0.f, 0.f, 0.f};
#pragma unroll
      for (int kk = 0; kk < 4; ++kk) {
        int byte = ((b * 16 + cl) * 256 + kk * 64 + kg * 16) ^ ((cl & 7) << 4);
        acc = __builtin_amdgcn_mfma_f32_16x16x32_bf16(af[kk], *(bf16x8*)((char*)Ba + byte), acc, 0, 0, 0);
        acw = __builtin_amdgcn_mfma_f32_16x16x32_bf16(af[kk], *(bf16x8*)((char*)Bb + byte), acw, 0, 0, 0);
      }
      int col = b * 16 + cl;
#pragma unroll
      for (int r = 0; r < 4; ++r) {
        long row = rbase + kg * 4 + r;
        u[row * DM + col] = acc[r];
        w[row * DM + col] = acw[r];
      }
    }
  }
}

// --- dst-degree count ---
__global__ __launch_bounds__(256)
void count_kernel(const int* __restrict__ ei, float* __restrict__ cnt)
{
  int e = blockIdx.x * 256 + threadIdx.x;
  if (e < EE) atomicAdd(&cnt[ei[EE + e]], 1.0f);
}

// --- fused edge kernel: r2 structure widened to 12 waves (131.6K LDS, 3 waves/SIMD) ---
__global__ __launch_bounds__(768, 2)
void edge_kernel(const float* __restrict__ u, const float* __restrict__ w,
                 const float* __restrict__ x, const float* __restrict__ ea,
                 const float* __restrict__ We1, const float* __restrict__ be1,
                 const float* __restrict__ We2, const float* __restrict__ be2,
                 const float* __restrict__ Wx1, const float* __restrict__ bx1,
                 const float* __restrict__ Wx2, const float* __restrict__ bx2,
                 const int* __restrict__ ei,
                 float* __restrict__ agg, float* __restrict__ crd)
{
  __shared__ unsigned short We2T[DM * DM];       // 32K
  __shared__ unsigned short Wx1T[DM * DM];       // 32K
  __shared__ unsigned short o1s[12][16 * DM];    // 48K
  __shared__ float mfs[12][64];                  // 3K
  __shared__ float eas[12][256];                 // 12K
  __shared__ int   mis[12][32];                  // 1.5K => ~128.5K

  const int tid = threadIdx.x;
  for (int idx = tid; idx < DM * DM; idx += 768) {
    int k = idx >> 7, n = idx & 127;
    int byte = (n * 256 + k * 2) ^ ((n & 7) << 4);
    *(unsigned short*)((char*)We2T + byte) = bf16rne(We2[idx]);
    *(unsigned short*)((char*)Wx1T + byte) = bf16rne(Wx1[idx]);
  }
  __syncthreads();

  const int lane = tid & 63;
  const int wv = tid >> 6;
  const int cl = lane & 15;
  const int kg = lane >> 4;
  const int c0 = lane * 2;
  unsigned short* o1 = o1s[wv];
  float* mfw = mfs[wv];
  float* eaw = eas[wv];
  int* miw = mis[wv];

  float wr[17][2];
#pragma unroll
  for (int t = 0; t < 17; ++t) {
    wr[t][0] = We1[(2 * DH + t) * DM + c0];
    wr[t][1] = We1[(2 * DH + t) * DM + c0 + 1];
  }
  const float be1a = be1[c0], be1b = be1[c0 + 1];
  float be2v[8], bx1v[8], wxr[8];
#pragma unroll
  for (int b = 0; b < 8; ++b) {
    be2v[b] = be2[b * 16 + cl];
    bx1v[b] = bx1[b * 16 + cl];
    wxr[b] = Wx2[b * 16 + cl];
  }
  const float bx2s = bx2[0];

  const int waveId = blockIdx.x * 12 + wv;
  const int nW = gridDim.x * 12;

  for (int tile = waveId; tile < EE / 16; tile += nW) {
    const int e0 = tile * 16;
    if (lane < 16) {
      int s = ei[e0 + lane];
      int d = ei[EE + e0 + lane];
      miw[lane] = s;
      miw[16 + lane] = d;
      float dx = x[s * 3 + 0] - x[d * 3 + 0];
      float dy = x[s * 3 + 1] - x[d * 3 + 1];
      float dz = x[s * 3 + 2] - x[d * 3 + 2];
      mfw[lane] = dx * dx + dy * dy + dz * dz;
      mfw[16 + lane] = dx;
      mfw[32 + lane] = dy;
      mfw[48 + lane] = dz;
    }
    ((float4*)eaw)[lane] = ((const float4*)(ea + (long)e0 * DE))[lane];

#pragma unroll
    for (int e = 0; e < 16; ++e) {
      int s = miw[e], d = miw[16 + e];
      float2 uu = *(const float2*)&u[(long)s * DM + c0];
      float2 ww = *(const float2*)&w[(long)d * DM + c0];
      float sq = mfw[e];
      float z0 = uu.x + ww.x + be1a + sq * wr[0][0];
      float z1 = uu.y + ww.y + be1b + sq * wr[0][1];
#pragma unroll
      for (int g = 0; g < 4; ++g) {
        float4 ev = *(const float4*)&eaw[e * 16 + 4 * g];
        z0 += ev.x * wr[1 + 4 * g][0]; z1 += ev.x * wr[1 + 4 * g][1];
        z0 += ev.y * wr[2 + 4 * g][0]; z1 += ev.y * wr[2 + 4 * g][1];
        z0 += ev.z * wr[3 + 4 * g][0]; z1 += ev.z * wr[3 + 4 * g][1];
        z0 += ev.w * wr[4 + 4 * g][0]; z1 += ev.w * wr[4 + 4 * g][1];
      }
      unsigned pk = ((unsigned)bf16rne(silu_f(z1)) << 16) | bf16rne(silu_f(z0));
      int byte = (e * 256 + c0 * 2) ^ ((e & 7) << 4);
      *(unsigned*)((char*)o1 + byte) = pk;
    }

    bf16x8 af[4];
#pragma unroll
    for (int kk = 0; kk < 4; ++kk) {
      int byte = (cl * 256 + kk * 64 + kg * 16) ^ ((cl & 7) << 4);
      af[kk] = *(bf16x8*)((char*)o1 + byte);
    }
    f32x4 acc[8];
#pragma unroll
    for (int b = 0; b < 8; ++b) {
      acc[b] = (f32x4){be2v[b], be2v[b], be2v[b], be2v[b]};
#pragma unroll
      for (int kk = 0; kk < 4; ++kk) {
        int byte = ((b * 16 + cl) * 256 + kk * 64 + kg * 16) ^ ((cl & 7) << 4);
        bf16x8 bfr = *(bf16x8*)((char*)We2T + byte);
        acc[b] = __builtin_amdgcn_mfma_f32_16x16x32_bf16(af[kk], bfr, acc[b], 0, 0, 0);
      }
    }

    const int rbase = kg * 4;
#pragma unroll
    for (int b = 0; b < 8; ++b) {
      int col = b * 16 + cl;
#pragma unroll
      for (int r = 0; r < 4; ++r) {
        int row = rbase + r;
        float m = silu_f(acc[b][r]);
        atomicAdd(&agg[(long)miw[16 + row] * DM + col], m);
        int byte = (row * 256 + col * 2) ^ ((row & 7) << 4);
        *(unsigned short*)((char*)o1 + byte) = bf16rne(m);
      }
    }

    bf16x8 af2[4];
#pragma unroll
    for (int kk = 0; kk < 4; ++kk) {
      int byte = (cl * 256 + kk * 64 + kg * 16) ^ ((cl & 7) << 4);
      af2[kk] = *(bf16x8*)((char*)o1 + byte);
    }
    f32x4 accx[8];
#pragma unroll
    for (int b = 0; b < 8; ++b) {
      accx[b] = (f32x4){bx1v[b], bx1v[b], bx1v[b], bx1v[b]};
#pragma unroll
      for (int kk = 0; kk < 4; ++kk) {
        int byte = ((b * 16 + cl) * 256 + kk * 64 + kg * 16) ^ ((cl & 7) << 4);
        bf16x8 bfr = *(bf16x8*)((char*)Wx1T + byte);
        accx[b] = __builtin_amdgcn_mfma_f32_16x16x32_bf16(af2[kk], bfr, accx[b], 0, 0, 0);
      }
    }

    float s0 = 0.f, s1 = 0.f, s2 = 0.f, s3 = 0.f;
#pragma unroll
    for (int b = 0; b < 8; ++b) {
      s0 += silu_f(accx[b][0]) * wxr[b];
      s1 += silu_f(accx[b][1]) * wxr[b];
      s2 += silu_f(accx[b][2]) * wxr[b];
      s3 += silu_f(accx[b][3]) * wxr[b];
    }
#pragma unroll
    for (int off = 1; off < 16; off <<= 1) {
      s0 += __shfl_xor(s0, off, 64);
      s1 += __shfl_xor(s1, off, 64);
      s2 += __shfl_xor(s2, off, 64);
      s3 += __shfl_xor(s3, off, 64);
    }

    if (cl < 12) {
      int r = cl / 3;
      int c = cl - 3 * r;
      float sv = (r == 0) ? s0 : ((r == 1) ? s1 : ((r == 2) ? s2 : s3));
      int row = rbase + r;
      float wgt = sv + bx2s;
      int s = miw[row];
      float dcomp = mfw[16 + c * 16 + row];
      atomicAdd(&crd[(long)s * 3 + c], dcomp * wgt);
    }
  }
}

// --- node update layer 1 via MFMA: t = silu([h, agg/cnt] @ Wh1 + bh1), bf16 out ---
__global__ __launch_bounds__(256, 2)
void upd1_mfma(const float* __restrict__ h, const float* __restrict__ agg,
               const float* __restrict__ cnt, const unsigned short* __restrict__ Wh1T,
               const float* __restrict__ bh1, unsigned short* __restrict__ t)
{
  __shared__ unsigned short B1[DM * 256];
  const int tid = threadIdx.x;
  for (int c = tid; c < 4096; c += 256) {
    int n = c >> 5, ck = c & 31;
    int sb = (n * 512 + ck * 16) ^ ((n & 7) << 4);
    *(bf16x8*)((char*)B1 + sb) = ((const bf16x8*)Wh1T)[c];
  }
  __syncthreads();
  const int lane = tid & 63, wv = tid >> 6;
  const int cl = lane & 15, kg = lane >> 4;
  float bh1v[8];
#pragma unroll
  for (int b = 0; b < 8; ++b) bh1v[b] = bh1[b * 16 + cl];
  const int waveId = blockIdx.x * 4 + wv, nW = gridDim.x * 4;
  for (int tile = waveId; tile < NN / 16; tile += nW) {
    const long rbase = (long)tile * 16;
    const float inv = __fdividef(1.0f, fmaxf(cnt[rbase + cl], 1.0f));
    bf16x8 af[8];
#pragma unroll
    for (int kk = 0; kk < 4; ++kk) {
      const float* hp = &h[(rbase + cl) * DH + kk * 32 + kg * 8];
      float4 a0 = *(const float4*)hp;
      float4 a1 = *(const float4*)(hp + 4);
      bf16x8 v;
      v[0] = (short)bf16rne(a0.x); v[1] = (short)bf16rne(a0.y);
      v[2] = (short)bf16rne(a0.z); v[3] = (short)bf16rne(a0.w);
      v[4] = (short)bf16rne(a1.x); v[5] = (short)bf16rne(a1.y);
      v[6] = (short)bf16rne(a1.z); v[7] = (short)bf16rne(a1.w);
      af[kk] = v;
    }
#pragma unroll
    for (int kk = 0; kk < 4; ++kk) {
      const float* ap = &agg[(rbase + cl) * DM + kk * 32 + kg * 8];
      float4 a0 = *(const float4*)ap;
      float4 a1 = *(const float4*)(ap + 4);
      bf16x8 v;
      v[0] = (short)bf16rne(a0.x * inv); v[1] = (short)bf16rne(a0.y * inv);
      v[2] = (short)bf16rne(a0.z * inv); v[3] = (short)bf16rne(a0.w * inv);
      v[4] = (short)bf16rne(a1.x * inv); v[5] = (short)bf16rne(a1.y * inv);
      v[6] = (short)bf16rne(a1.z * inv); v[7] = (short)bf16rne(a1.w * inv);
      af[4 + kk] = v;
    }
#pragma unroll
    for (int b = 0; b < 8; ++b) {
      f32x4 acc = (f32x4){bh1v[b], bh1v[b], bh1v[b], bh1v[b]};
#pragma unroll
      for (int kk = 0; kk < 8; ++kk) {
        int byte = ((b * 16 + cl) * 512 + kk * 64 + kg * 16) ^ ((cl & 7) << 4);
        acc = __builtin_amdgcn_mfma_f32_16x16x32_bf16(af[kk], *(bf16x8*)((char*)B1 + byte), acc, 0, 0, 0);
      }
      int col = b * 16 + cl;
#pragma unroll
      for (int r = 0; r < 4; ++r) {
        long row = rbase + kg * 4 + r;
        t[row * DM + col] = bf16rne(silu_f(acc[r]));
      }
    }
  }
}

// --- node update layer 2 via MFMA + residual + layernorm ---
__global__ __launch_bounds__(256, 2)
void upd2_mfma(const unsigned short* __restrict__ t, const float* __restrict__ h,
               const unsigned short* __restrict__ Wh2T, const float* __restrict__ bh2,
               const float* __restrict__ lng, const float* __restrict__ lnb,
               float* __restrict__ out)
{
  __shared__ unsigned short B2[DM * DM];
  const int tid = threadIdx.x;
  for (int c = tid; c < 2048; c += 256) {
    int n = c >> 4, ck = c & 15;
    int sb = (n * 256 + ck * 16) ^ ((n & 7) << 4);
    *(bf16x8*)((char*)B2 + sb) = ((const bf16x8*)Wh2T)[c];
  }
  __syncthreads();
  const int lane = tid & 63, wv = tid >> 6;
  const int cl = lane & 15, kg = lane >> 4;
  float bh2v[8], gv[8], qv[8];
#pragma unroll
  for (int b = 0; b < 8; ++b) {
    bh2v[b] = bh2[b * 16 + cl];
    gv[b] = lng[b * 16 + cl];
    qv[b] = lnb[b * 16 + cl];
  }
  const int waveId = blockIdx.x * 4 + wv, nW = gridDim.x * 4;
  for (int tile = waveId; tile < NN / 16; tile += nW) {
    const long rbase = (long)tile * 16;
    bf16x8 af[4];
#pragma unroll
    for (int kk = 0; kk < 4; ++kk)
      af[kk] = *(const bf16x8*)&t[(rbase + cl) * DM + kk * 32 + kg * 8];
    float pre[8][4];
#pragma unroll
    for (int b = 0; b < 8; ++b) {
      f32x4 acc = (f32x4){bh2v[b], bh2v[b], bh2v[b], bh2v[b]};
#pragma unroll
      for (int kk = 0; kk < 4; ++kk) {
        int byte = ((b * 16 + cl) * 256 + kk * 64 + kg * 16) ^ ((cl & 7) << 4);
        acc = __builtin_amdgcn_mfma_f32_16x16x32_bf16(af[kk], *(bf16x8*)((char*)B2 + byte), acc, 0, 0, 0);
      }
      int col = b * 16 + cl;
#pragma unroll
      for (int r = 0; r < 4; ++r)
        pre[b][r] = acc[r] + h[(rbase + kg * 4 + r) * DH + col];
    }
#pragma unroll
    for (int r = 0; r < 4; ++r) {
      float s = 0.f, q = 0.f;
#pragma unroll
      for (int b = 0; b < 8; ++b) { s += pre[b][r]; q += pre[b][r] * pre[b][r]; }
#pragma unroll
      for (int off = 1; off < 16; off <<= 1) {
        s += __shfl_xor(s, off, 64);
        q += __shfl_xor(q, off, 64);
      }
      float mean = s * (1.0f / 128.0f);
      float var = q * (1.0f / 128.0f) - mean * mean;
      float rs = rsqrtf(var + 1e-5f);
      long row = rbase + kg * 4 + r;
#pragma unroll
      for (int b = 0; b < 8; ++b) {
        out[row * DM + b * 16 + cl] = (pre[b][r] - mean) * rs * gv[b] + qv[b];
      }
    }
  }
}

// --- x output ---
__global__ __launch_bounds__(256)
void xout_kernel(const float* __restrict__ x, const float* __restrict__ crd,
                 const float* __restrict__ cnt, float* __restrict__ out)
{
  int i = blockIdx.x * 256 + threadIdx.x;
  if (i < NN * 3) {
    int n = i / 3;
    float cv = fmaxf(cnt[n], 1.0f);
    out[i] = x[i] + crd[i] * __fdividef(1.0f, cv);
  }
}

extern "C" void kernel_launch(void* const* d_in, const int* in_sizes, int n_in,
                              void* d_out, int out_size, void* d_ws, size_t ws_size,
                              hipStream_t stream)
{
  (void)in_sizes; (void)n_in; (void)out_size; (void)ws_size;
  const float* h   = (const float*)d_in[0];
  const float* x   = (const float*)d_in[1];
  const float* ea  = (const float*)d_in[2];
  const float* We1 = (const float*)d_in[3];
  const float* be1 = (const float*)d_in[4];
  const float* We2 = (const float*)d_in[5];
  const float* be2 = (const float*)d_in[6];
  const float* Wh1 = (const float*)d_in[7];
  const float* bh1 = (const float*)d_in[8];
  const float* Wh2 = (const float*)d_in[9];
  const float* bh2 = (const float*)d_in[10];
  const float* Wx1 = (const float*)d_in[11];
  const float* bx1 = (const float*)d_in[12];
  const float* Wx2 = (const float*)d_in[13];
  const float* bx2 = (const float*)d_in[14];
  const float* lng = (const float*)d_in[15];
  const float* lnb = (const float*)d_in[16];
  const int*   ei  = (const int*)d_in[17];
  float* out = (float*)d_out;
  float* ws  = (float*)d_ws;

  float* u   = ws;                 // N*128 fp32
  float* w   = ws + 6400000;       // N*128 fp32
  float* agg = ws + 12800000;      // N*128 fp32
  float* cnt = ws + 19200000;      // N
  float* crd = ws + 19250000;      // N*3
  unsigned short* WeaT = (unsigned short*)(ws + 19400000);  // 128*128
  unsigned short* WebT = WeaT + 16384;                      // 128*128
  unsigned short* Wh1T = WebT + 16384;                      // 128*256
  unsigned short* Wh2T = Wh1T + 32768;                      // 128*128
  unsigned short* tbf  = (unsigned short*)w;                // reuse w after edge

  hipMemsetAsync(agg, 0, (6400000 + 50000 + 150000) * sizeof(float), stream);

  prep_wt_kernel<<<128, 256, 0, stream>>>(We1, Wh1, Wh2, WeaT, WebT, Wh1T, Wh2T);
  node_pre_mfma<<<782, 256, 0, stream>>>(h, WeaT, WebT, u, w);
  count_kernel<<<(EE + 255) / 256, 256, 0, stream>>>(ei, cnt);
  edge_kernel<<<256, 768, 0, stream>>>(u, w, x, ea, We1, be1, We2, be2,
                                       Wx1, bx1, Wx2, bx2, ei, agg, crd);
  upd1_mfma<<<782, 256, 0, stream>>>(h, agg, cnt, Wh1T, bh1, tbf);
  upd2_mfma<<<782, 256, 0, stream>>>(tbf, h, Wh2T, bh2, lng, lnb, out);
  xout_kernel<<<(NN * 3 + 255) / 256, 256, 0, stream>>>(x, crd, cnt, out + 6400000);
}

// Round 15
// 659.636 us; speedup vs baseline: 1.1565x; 1.1565x over previous
//
#include <hip/hip_runtime.h>

constexpr int NN = 50000;
constexpr int EE = 800000;
constexpr int DH = 128;
constexpr int DE = 16;
constexpr int DM = 128;

typedef short bf16x8 __attribute__((ext_vector_type(8)));
typedef float f32x4 __attribute__((ext_vector_type(4)));

__device__ __forceinline__ float silu_f(float z) {
  return __fdividef(z, 1.0f + __expf(-z));
}
__device__ __forceinline__ unsigned short bf16rne(float f) {
  unsigned u = __float_as_uint(f);
  return (unsigned short)((u + 0x7FFFu + ((u >> 16) & 1u)) >> 16);
}

// --- prep: transpose weights to bf16 [n][k] row-major in global ---
__global__ __launch_bounds__(256)
void prep_wt_kernel(const float* __restrict__ We1, const float* __restrict__ Wh1,
                    const float* __restrict__ Wh2,
                    unsigned short* __restrict__ WeaT, unsigned short* __restrict__ WebT,
                    unsigned short* __restrict__ Wh1T, unsigned short* __restrict__ Wh2T)
{
  int i = blockIdx.x * 256 + threadIdx.x;
  if (i < 16384) {
    int n = i >> 7, k = i & 127;
    WeaT[n * 128 + k] = bf16rne(We1[k * DM + n]);
    WebT[n * 128 + k] = bf16rne(We1[(DH + k) * DM + n]);
    Wh2T[n * 128 + k] = bf16rne(Wh2[k * DM + n]);
  }
  if (i < 32768) {
    int n = i >> 8, k = i & 255;
    Wh1T[n * 256 + k] = bf16rne(Wh1[k * DM + n]);
  }
}

// --- node precompute via MFMA: u = h @ We1[0:128], w = h @ We1[128:256] ---
__global__ __launch_bounds__(256, 2)
void node_pre_mfma(const float* __restrict__ h,
                   const unsigned short* __restrict__ WeaT,
                   const unsigned short* __restrict__ WebT,
                   float* __restrict__ u, float* __restrict__ w)
{
  __shared__ unsigned short Ba[DM * DM];  // swizzled: byte ^= (n&7)<<4
  __shared__ unsigned short Bb[DM * DM];
  const int tid = threadIdx.x;
  for (int c = tid; c < 2048; c += 256) {
    int n = c >> 4, ck = c & 15;   // 16 chunks of 8 per 128-elem row
    int sb = (n * 256 + ck * 16) ^ ((n & 7) << 4);
    *(bf16x8*)((char*)Ba + sb) = ((const bf16x8*)WeaT)[c];
    *(bf16x8*)((char*)Bb + sb) = ((const bf16x8*)WebT)[c];
  }
  __syncthreads();
  const int lane = tid & 63, wv = tid >> 6;
  const int cl = lane & 15, kg = lane >> 4;
  const int waveId = blockIdx.x * 4 + wv, nW = gridDim.x * 4;
  for (int tile = waveId; tile < NN / 16; tile += nW) {
    const long rbase = (long)tile * 16;
    bf16x8 af[4];
#pragma unroll
    for (int kk = 0; kk < 4; ++kk) {
      const float* hp = &h[(rbase + cl) * DH + kk * 32 + kg * 8];
      float4 a0 = *(const float4*)hp;
      float4 a1 = *(const float4*)(hp + 4);
      bf16x8 v;
      v[0] = (short)bf16rne(a0.x); v[1] = (short)bf16rne(a0.y);
      v[2] = (short)bf16rne(a0.z); v[3] = (short)bf16rne(a0.w);
      v[4] = (short)bf16rne(a1.x); v[5] = (short)bf16rne(a1.y);
      v[6] = (short)bf16rne(a1.z); v[7] = (short)bf16rne(a1.w);
      af[kk] = v;
    }
#pragma unroll
    for (int b = 0; b < 8; ++b) {
      f32x4 acc = (f32x4){0.f, 0.f, 0.f, 0.f};
      f32x4 acw = (f32x4){0.f, 0.f, 0.f, 0.f};
#pragma unroll
      for (int kk = 0; kk < 4; ++kk) {
        int byte = ((b * 16 + cl) * 256 + kk * 64 + kg * 16) ^ ((cl & 7) << 4);
        acc = __builtin_amdgcn_mfma_f32_16x16x32_bf16(af[kk], *(bf16x8*)((char*)Ba + byte), acc, 0, 0, 0);
        acw = __builtin_amdgcn_mfma_f32_16x16x32_bf16(af[kk], *(bf16x8*)((char*)Bb + byte), acw, 0, 0, 0);
      }
      int col = b * 16 + cl;
#pragma unroll
      for (int r = 0; r < 4; ++r) {
        long row = rbase + kg * 4 + r;
        u[row * DM + col] = acc[r];
        w[row * DM + col] = acw[r];
      }
    }
  }
}

// --- dst-degree count ---
__global__ __launch_bounds__(256)
void count_kernel(const int* __restrict__ ei, float* __restrict__ cnt)
{
  int e = blockIdx.x * 256 + threadIdx.x;
  if (e < EE) atomicAdd(&cnt[ei[EE + e]], 1.0f);
}

// --- fused edge kernel: EXACT round-2 structure (best verified: 555 us) ---
__global__ __launch_bounds__(512, 2)
void edge_kernel(const float* __restrict__ u, const float* __restrict__ w,
                 const float* __restrict__ x, const float* __restrict__ ea,
                 const float* __restrict__ We1, const float* __restrict__ be1,
                 const float* __restrict__ We2, const float* __restrict__ be2,
                 const float* __restrict__ Wx1, const float* __restrict__ bx1,
                 const float* __restrict__ Wx2, const float* __restrict__ bx2,
                 const int* __restrict__ ei,
                 float* __restrict__ agg, float* __restrict__ crd)
{
  __shared__ unsigned short We2T[DM * DM];
  __shared__ unsigned short Wx1T[DM * DM];
  __shared__ unsigned short o1s[8][16 * DM];
  __shared__ float mfs[8][64];
  __shared__ float eas[8][256];
  __shared__ int   mis[8][32];

  const int tid = threadIdx.x;
  for (int idx = tid; idx < DM * DM; idx += 512) {
    int k = idx >> 7, n = idx & 127;
    int byte = (n * 256 + k * 2) ^ ((n & 7) << 4);
    *(unsigned short*)((char*)We2T + byte) = bf16rne(We2[idx]);
    *(unsigned short*)((char*)Wx1T + byte) = bf16rne(Wx1[idx]);
  }
  __syncthreads();

  const int lane = tid & 63;
  const int wv = tid >> 6;
  const int cl = lane & 15;
  const int kg = lane >> 4;
  const int c0 = lane * 2;
  unsigned short* o1 = o1s[wv];
  float* mfw = mfs[wv];
  float* eaw = eas[wv];
  int* miw = mis[wv];

  float wr[17][2];
#pragma unroll
  for (int t = 0; t < 17; ++t) {
    wr[t][0] = We1[(2 * DH + t) * DM + c0];
    wr[t][1] = We1[(2 * DH + t) * DM + c0 + 1];
  }
  const float be1a = be1[c0], be1b = be1[c0 + 1];
  float be2v[8], bx1v[8], wxr[8];
#pragma unroll
  for (int b = 0; b < 8; ++b) {
    be2v[b] = be2[b * 16 + cl];
    bx1v[b] = bx1[b * 16 + cl];
    wxr[b] = Wx2[b * 16 + cl];
  }
  const float bx2s = bx2[0];

  const int waveId = blockIdx.x * 8 + wv;
  const int nW = gridDim.x * 8;

  for (int tile = waveId; tile < EE / 16; tile += nW) {
    const int e0 = tile * 16;
    if (lane < 16) {
      int s = ei[e0 + lane];
      int d = ei[EE + e0 + lane];
      miw[lane] = s;
      miw[16 + lane] = d;
      float dx = x[s * 3 + 0] - x[d * 3 + 0];
      float dy = x[s * 3 + 1] - x[d * 3 + 1];
      float dz = x[s * 3 + 2] - x[d * 3 + 2];
      mfw[lane] = dx * dx + dy * dy + dz * dz;
      mfw[16 + lane] = dx;
      mfw[32 + lane] = dy;
      mfw[48 + lane] = dz;
    }
    ((float4*)eaw)[lane] = ((const float4*)(ea + (long)e0 * DE))[lane];

#pragma unroll
    for (int e = 0; e < 16; ++e) {
      int s = miw[e], d = miw[16 + e];
      float2 uu = *(const float2*)&u[(long)s * DM + c0];
      float2 ww = *(const float2*)&w[(long)d * DM + c0];
      float sq = mfw[e];
      float z0 = uu.x + ww.x + be1a + sq * wr[0][0];
      float z1 = uu.y + ww.y + be1b + sq * wr[0][1];
#pragma unroll
      for (int g = 0; g < 4; ++g) {
        float4 ev = *(const float4*)&eaw[e * 16 + 4 * g];
        z0 += ev.x * wr[1 + 4 * g][0]; z1 += ev.x * wr[1 + 4 * g][1];
        z0 += ev.y * wr[2 + 4 * g][0]; z1 += ev.y * wr[2 + 4 * g][1];
        z0 += ev.z * wr[3 + 4 * g][0]; z1 += ev.z * wr[3 + 4 * g][1];
        z0 += ev.w * wr[4 + 4 * g][0]; z1 += ev.w * wr[4 + 4 * g][1];
      }
      unsigned pk = ((unsigned)bf16rne(silu_f(z1)) << 16) | bf16rne(silu_f(z0));
      int byte = (e * 256 + c0 * 2) ^ ((e & 7) << 4);
      *(unsigned*)((char*)o1 + byte) = pk;
    }

    bf16x8 af[4];
#pragma unroll
    for (int kk = 0; kk < 4; ++kk) {
      int byte = (cl * 256 + kk * 64 + kg * 16) ^ ((cl & 7) << 4);
      af[kk] = *(bf16x8*)((char*)o1 + byte);
    }
    f32x4 acc[8];
#pragma unroll
    for (int b = 0; b < 8; ++b) {
      acc[b] = (f32x4){be2v[b], be2v[b], be2v[b], be2v[b]};
#pragma unroll
      for (int kk = 0; kk < 4; ++kk) {
        int byte = ((b * 16 + cl) * 256 + kk * 64 + kg * 16) ^ ((cl & 7) << 4);
        bf16x8 bfr = *(bf16x8*)((char*)We2T + byte);
        acc[b] = __builtin_amdgcn_mfma_f32_16x16x32_bf16(af[kk], bfr, acc[b], 0, 0, 0);
      }
    }

    const int rbase = kg * 4;
#pragma unroll
    for (int b = 0; b < 8; ++b) {
      int col = b * 16 + cl;
#pragma unroll
      for (int r = 0; r < 4; ++r) {
        int row = rbase + r;
        float m = silu_f(acc[b][r]);
        atomicAdd(&agg[(long)miw[16 + row] * DM + col], m);
        int byte = (row * 256 + col * 2) ^ ((row & 7) << 4);
        *(unsigned short*)((char*)o1 + byte) = bf16rne(m);
      }
    }

    bf16x8 af2[4];
#pragma unroll
    for (int kk = 0; kk < 4; ++kk) {
      int byte = (cl * 256 + kk * 64 + kg * 16) ^ ((cl & 7) << 4);
      af2[kk] = *(bf16x8*)((char*)o1 + byte);
    }
    f32x4 accx[8];
#pragma unroll
    for (int b = 0; b < 8; ++b) {
      accx[b] = (f32x4){bx1v[b], bx1v[b], bx1v[b], bx1v[b]};
#pragma unroll
      for (int kk = 0; kk < 4; ++kk) {
        int byte = ((b * 16 + cl) * 256 + kk * 64 + kg * 16) ^ ((cl & 7) << 4);
        bf16x8 bfr = *(bf16x8*)((char*)Wx1T + byte);
        accx[b] = __builtin_amdgcn_mfma_f32_16x16x32_bf16(af2[kk], bfr, accx[b], 0, 0, 0);
      }
    }

    float s0 = 0.f, s1 = 0.f, s2 = 0.f, s3 = 0.f;
#pragma unroll
    for (int b = 0; b < 8; ++b) {
      s0 += silu_f(accx[b][0]) * wxr[b];
      s1 += silu_f(accx[b][1]) * wxr[b];
      s2 += silu_f(accx[b][2]) * wxr[b];
      s3 += silu_f(accx[b][3]) * wxr[b];
    }
#pragma unroll
    for (int off = 1; off < 16; off <<= 1) {
      s0 += __shfl_xor(s0, off, 64);
      s1 += __shfl_xor(s1, off, 64);
      s2 += __shfl_xor(s2, off, 64);
      s3 += __shfl_xor(s3, off, 64);
    }

    if (cl < 12) {
      int r = cl / 3;
      int c = cl - 3 * r;
      float sv = (r == 0) ? s0 : ((r == 1) ? s1 : ((r == 2) ? s2 : s3));
      int row = rbase + r;
      float wgt = sv + bx2s;
      int s = miw[row];
      float dcomp = mfw[16 + c * 16 + row];
      atomicAdd(&crd[(long)s * 3 + c], dcomp * wgt);
    }
  }
}

// --- node update layer 1 via MFMA: t = silu([h, agg/cnt] @ Wh1 + bh1), bf16 out ---
__global__ __launch_bounds__(256, 2)
void upd1_mfma(const float* __restrict__ h, const float* __restrict__ agg,
               const float* __restrict__ cnt, const unsigned short* __restrict__ Wh1T,
               const float* __restrict__ bh1, unsigned short* __restrict__ t)
{
  __shared__ unsigned short B1[DM * 256];  // [n][k=256], swizzled byte ^= (n&7)<<4
  const int tid = threadIdx.x;
  for (int c = tid; c < 4096; c += 256) {
    int n = c >> 5, ck = c & 31;   // 32 chunks of 8 per 256-elem row
    int sb = (n * 512 + ck * 16) ^ ((n & 7) << 4);
    *(bf16x8*)((char*)B1 + sb) = ((const bf16x8*)Wh1T)[c];
  }
  __syncthreads();
  const int lane = tid & 63, wv = tid >> 6;
  const int cl = lane & 15, kg = lane >> 4;
  float bh1v[8];
#pragma unroll
  for (int b = 0; b < 8; ++b) bh1v[b] = bh1[b * 16 + cl];
  const int waveId = blockIdx.x * 4 + wv, nW = gridDim.x * 4;
  for (int tile = waveId; tile < NN / 16; tile += nW) {
    const long rbase = (long)tile * 16;
    const float inv = __fdividef(1.0f, fmaxf(cnt[rbase + cl], 1.0f));
    bf16x8 af[8];
#pragma unroll
    for (int kk = 0; kk < 4; ++kk) {
      const float* hp = &h[(rbase + cl) * DH + kk * 32 + kg * 8];
      float4 a0 = *(const float4*)hp;
      float4 a1 = *(const float4*)(hp + 4);
      bf16x8 v;
      v[0] = (short)bf16rne(a0.x); v[1] = (short)bf16rne(a0.y);
      v[2] = (short)bf16rne(a0.z); v[3] = (short)bf16rne(a0.w);
      v[4] = (short)bf16rne(a1.x); v[5] = (short)bf16rne(a1.y);
      v[6] = (short)bf16rne(a1.z); v[7] = (short)bf16rne(a1.w);
      af[kk] = v;
    }
#pragma unroll
    for (int kk = 0; kk < 4; ++kk) {
      const float* ap = &agg[(rbase + cl) * DM + kk * 32 + kg * 8];
      float4 a0 = *(const float4*)ap;
      float4 a1 = *(const float4*)(ap + 4);
      bf16x8 v;
      v[0] = (short)bf16rne(a0.x * inv); v[1] = (short)bf16rne(a0.y * inv);
      v[2] = (short)bf16rne(a0.z * inv); v[3] = (short)bf16rne(a0.w * inv);
      v[4] = (short)bf16rne(a1.x * inv); v[5] = (short)bf16rne(a1.y * inv);
      v[6] = (short)bf16rne(a1.z * inv); v[7] = (short)bf16rne(a1.w * inv);
      af[4 + kk] = v;
    }
#pragma unroll
    for (int b = 0; b < 8; ++b) {
      f32x4 acc = (f32x4){bh1v[b], bh1v[b], bh1v[b], bh1v[b]};
#pragma unroll
      for (int kk = 0; kk < 8; ++kk) {
        int byte = ((b * 16 + cl) * 512 + kk * 64 + kg * 16) ^ ((cl & 7) << 4);
        acc = __builtin_amdgcn_mfma_f32_16x16x32_bf16(af[kk], *(bf16x8*)((char*)B1 + byte), acc, 0, 0, 0);
      }
      int col = b * 16 + cl;
#pragma unroll
      for (int r = 0; r < 4; ++r) {
        long row = rbase + kg * 4 + r;
        t[row * DM + col] = bf16rne(silu_f(acc[r]));
      }
    }
  }
}

// --- node update layer 2 via MFMA + residual + layernorm ---
__global__ __launch_bounds__(256, 2)
void upd2_mfma(const unsigned short* __restrict__ t, const float* __restrict__ h,
               const unsigned short* __restrict__ Wh2T, const float* __restrict__ bh2,
               const float* __restrict__ lng, const float* __restrict__ lnb,
               float* __restrict__ out)
{
  __shared__ unsigned short B2[DM * DM];
  const int tid = threadIdx.x;
  for (int c = tid; c < 2048; c += 256) {
    int n = c >> 4, ck = c & 15;   // 16 chunks of 8 per 128-elem row
    int sb = (n * 256 + ck * 16) ^ ((n & 7) << 4);
    *(bf16x8*)((char*)B2 + sb) = ((const bf16x8*)Wh2T)[c];
  }
  __syncthreads();
  const int lane = tid & 63, wv = tid >> 6;
  const int cl = lane & 15, kg = lane >> 4;
  float bh2v[8], gv[8], qv[8];
#pragma unroll
  for (int b = 0; b < 8; ++b) {
    bh2v[b] = bh2[b * 16 + cl];
    gv[b] = lng[b * 16 + cl];
    qv[b] = lnb[b * 16 + cl];
  }
  const int waveId = blockIdx.x * 4 + wv, nW = gridDim.x * 4;
  for (int tile = waveId; tile < NN / 16; tile += nW) {
    const long rbase = (long)tile * 16;
    bf16x8 af[4];
#pragma unroll
    for (int kk = 0; kk < 4; ++kk)
      af[kk] = *(const bf16x8*)&t[(rbase + cl) * DM + kk * 32 + kg * 8];
    float pre[8][4];
#pragma unroll
    for (int b = 0; b < 8; ++b) {
      f32x4 acc = (f32x4){bh2v[b], bh2v[b], bh2v[b], bh2v[b]};
#pragma unroll
      for (int kk = 0; kk < 4; ++kk) {
        int byte = ((b * 16 + cl) * 256 + kk * 64 + kg * 16) ^ ((cl & 7) << 4);
        acc = __builtin_amdgcn_mfma_f32_16x16x32_bf16(af[kk], *(bf16x8*)((char*)B2 + byte), acc, 0, 0, 0);
      }
      int col = b * 16 + cl;
#pragma unroll
      for (int r = 0; r < 4; ++r)
        pre[b][r] = acc[r] + h[(rbase + kg * 4 + r) * DH + col];
    }
#pragma unroll
    for (int r = 0; r < 4; ++r) {
      float s = 0.f, q = 0.f;
#pragma unroll
      for (int b = 0; b < 8; ++b) { s += pre[b][r]; q += pre[b][r] * pre[b][r]; }
#pragma unroll
      for (int off = 1; off < 16; off <<= 1) {
        s += __shfl_xor(s, off, 64);
        q += __shfl_xor(q, off, 64);
      }
      float mean = s * (1.0f / 128.0f);
      float var = q * (1.0f / 128.0f) - mean * mean;
      float rs = rsqrtf(var + 1e-5f);
      long row = rbase + kg * 4 + r;
#pragma unroll
      for (int b = 0; b < 8; ++b) {
        out[row * DM + b * 16 + cl] = (pre[b][r] - mean) * rs * gv[b] + qv[b];
      }
    }
  }
}

// --- x output ---
__global__ __launch_bounds__(256)
void xout_kernel(const float* __restrict__ x, const float* __restrict__ crd,
                 const float* __restrict__ cnt, float* __restrict__ out)
{
  int i = blockIdx.x * 256 + threadIdx.x;
  if (i < NN * 3) {
    int n = i / 3;
    float cv = fmaxf(cnt[n], 1.0f);
    out[i] = x[i] + crd[i] * __fdividef(1.0f, cv);
  }
}

extern "C" void kernel_launch(void* const* d_in, const int* in_sizes, int n_in,
                              void* d_out, int out_size, void* d_ws, size_t ws_size,
                              hipStream_t stream)
{
  (void)in_sizes; (void)n_in; (void)out_size; (void)ws_size;
  const float* h   = (const float*)d_in[0];
  const float* x   = (const float*)d_in[1];
  const float* ea  = (const float*)d_in[2];
  const float* We1 = (const float*)d_in[3];
  const float* be1 = (const float*)d_in[4];
  const float* We2 = (const float*)d_in[5];
  const float* be2 = (const float*)d_in[6];
  const float* Wh1 = (const float*)d_in[7];
  const float* bh1 = (const float*)d_in[8];
  const float* Wh2 = (const float*)d_in[9];
  const float* bh2 = (const float*)d_in[10];
  const float* Wx1 = (const float*)d_in[11];
  const float* bx1 = (const float*)d_in[12];
  const float* Wx2 = (const float*)d_in[13];
  const float* bx2 = (const float*)d_in[14];
  const float* lng = (const float*)d_in[15];
  const float* lnb = (const float*)d_in[16];
  const int*   ei  = (const int*)d_in[17];
  float* out = (float*)d_out;
  float* ws  = (float*)d_ws;

  float* u   = ws;                 // N*128 fp32
  float* w   = ws + 6400000;       // N*128 fp32
  float* agg = ws + 12800000;      // N*128 fp32
  float* cnt = ws + 19200000;      // N
  float* crd = ws + 19250000;      // N*3
  unsigned short* WeaT = (unsigned short*)(ws + 19400000);  // 128*128
  unsigned short* WebT = WeaT + 16384;                      // 128*128
  unsigned short* Wh1T = WebT + 16384;                      // 128*256
  unsigned short* Wh2T = Wh1T + 32768;                      // 128*128
  unsigned short* tbf  = (unsigned short*)w;                // reuse w after edge

  hipMemsetAsync(agg, 0, (6400000 + 50000 + 150000) * sizeof(float), stream);

  prep_wt_kernel<<<128, 256, 0, stream>>>(We1, Wh1, Wh2, WeaT, WebT, Wh1T, Wh2T);
  node_pre_mfma<<<782, 256, 0, stream>>>(h, WeaT, WebT, u, w);
  count_kernel<<<(EE + 255) / 256, 256, 0, stream>>>(ei, cnt);
  edge_kernel<<<256, 512, 0, stream>>>(u, w, x, ea, We1, be1, We2, be2,
                                       Wx1, bx1, Wx2, bx2, ei, agg, crd);
  upd1_mfma<<<782, 256, 0, stream>>>(h, agg, cnt, Wh1T, bh1, tbf);
  upd2_mfma<<<782, 256, 0, stream>>>(tbf, h, Wh2T, bh2, lng, lnb, out);
  xout_kernel<<<(NN * 3 + 255) / 256, 256, 0, stream>>>(x, crd, cnt, out + 6400000);
}